// Round 2
// 668.485 us; speedup vs baseline: 1.0327x; 1.0327x over previous
//
#include <hip/hip_runtime.h>
#include <stdint.h>

typedef unsigned short u16;
typedef __bf16 v8bf __attribute__((ext_vector_type(8)));
typedef float v4f __attribute__((ext_vector_type(4)));
typedef __attribute__((address_space(3))) unsigned lds_t;
typedef const __attribute__((address_space(1))) unsigned g_t;

__device__ __forceinline__ u16 f2bf(float f) {
  union { float f; unsigned u; } v; v.f = f;
  unsigned r = v.u + 0x7FFFu + ((v.u >> 16) & 1u);   // RNE
  return (u16)(r >> 16);
}
__device__ __forceinline__ float bf2f(u16 h) {
  union { unsigned u; float f; } v; v.u = ((unsigned)h) << 16;
  return v.f;
}
__device__ __forceinline__ long sel4(long4 v, int z) {
  return z == 0 ? v.x : z == 1 ? v.y : z == 2 ? v.z : v.w;
}
__device__ __forceinline__ int sel4i(int4 v, int z) {
  return z == 0 ? v.x : z == 1 ? v.y : z == 2 ? v.z : v.w;
}

// ---------------- fp32 -> bf16 convert ----------------
__global__ void k_cvt(const float* __restrict__ s, u16* __restrict__ d, long n) {
  long i = ((long)blockIdx.x * blockDim.x + threadIdx.x) * 4;
  long stride = (long)gridDim.x * blockDim.x * 4;
  for (; i < n; i += stride) {
    float4 f = *(const float4*)(s + i);
    ushort4 o;
    o.x = f2bf(f.x); o.y = f2bf(f.y); o.z = f2bf(f.z); o.w = f2bf(f.w);
    *(ushort4*)(d + i) = o;
  }
}

// ---------------- fp32 -> bf16 transpose-convert (32x32 tiles, batched z) ----
// dst[z][c][r] = bf16(src[z][r][c]);  R,C multiples of 32; 256 threads
__global__ void k_tc(const float* __restrict__ src, u16* __restrict__ dst, int R, int C) {
  __shared__ float t[32][33];
  long zoff = (long)blockIdx.z * R * C;
  int r0 = blockIdx.y * 32, c0 = blockIdx.x * 32;
  int tx = threadIdx.x & 31, ty = threadIdx.x >> 5;     // ty in [0,8)
#pragma unroll
  for (int j = 0; j < 32; j += 8)
    t[ty + j][tx] = src[zoff + (long)(r0 + ty + j) * C + c0 + tx];
  __syncthreads();
#pragma unroll
  for (int j = 0; j < 32; j += 8)
    dst[zoff + (long)(c0 + ty + j) * R + r0 + tx] = f2bf(t[tx][ty + j]);
}

// ---------------- input-side pooling: s=2,4,8 in one pass (fp32 src) --------
// src: (4,2048,1024) fp32. dst rows (1024-wide bf16):
//   s=2 -> 8192 + b*1024 + t', s=4 -> 12288 + b*512 + t', s=8 -> 14336 + b*256 + t'
__global__ void k_pool3(const float* __restrict__ src, u16* __restrict__ dst) {
  int idx = blockIdx.x;               // b(4) x g(256) x cc(4)
  int cc = idx & 3, g = (idx >> 2) & 255, b = idx >> 10;
  int c = cc * 256 + threadIdx.x;
  const float* p = src + ((long)b * 2048 + g * 8) * 1024 + c;
  float x[8];
#pragma unroll
  for (int j = 0; j < 8; j++) x[j] = p[(long)j * 1024];
  float s2[4], s4[2];
#pragma unroll
  for (int j = 0; j < 4; j++) s2[j] = x[2 * j] + x[2 * j + 1];
  s4[0] = s2[0] + s2[1]; s4[1] = s2[2] + s2[3];
  float s8 = s4[0] + s4[1];
  u16* d2 = dst + ((long)8192 + b * 1024 + g * 4) * 1024 + c;
#pragma unroll
  for (int j = 0; j < 4; j++) d2[(long)j * 1024] = f2bf(s2[j] * 0.5f);
  u16* d4 = dst + ((long)12288 + b * 512 + g * 2) * 1024 + c;
  d4[0] = f2bf(s4[0] * 0.25f); d4[1024] = f2bf(s4[1] * 0.25f);
  dst[((long)14336 + b * 256 + g) * 1024 + c] = f2bf(s8 * 0.125f);
}

// ---------------- bias combines (fp32) ----------------
// Bc[p*1024 + i*256 + of] = in_b[i][p*256+of] + sum_k in_w[i][p*256+of][k]*bp[i*256+k]
__global__ void k_bcomb_qkv(const float* __restrict__ in_w, const float* __restrict__ in_b,
                            const float* __restrict__ bq, const float* __restrict__ bk,
                            const float* __restrict__ bv, float* __restrict__ out) {
  int gw = (blockIdx.x * 256 + threadIdx.x) >> 6;   // 0..3071
  int lane = threadIdx.x & 63;
  int p = gw >> 10, j = gw & 1023, i = j >> 8, of = j & 255;
  const float* bp = p == 0 ? bq : p == 1 ? bk : bv;
  const float* row = in_w + ((long)i * 768 + p * 256 + of) * 256;
  float s = 0.f;
#pragma unroll
  for (int m = 0; m < 4; m++) s += row[lane + m * 64] * bp[i * 256 + lane + m * 64];
#pragma unroll
  for (int m = 32; m >= 1; m >>= 1) s += __shfl_xor(s, m, 64);
  if (lane == 0) out[gw] = in_b[(long)i * 768 + p * 256 + of] + s;
}

// fbc[of] = fus_b[of] + sum_k fus_w[of][k] * out_b_flat[k]
__global__ void k_bcomb_f(const float* __restrict__ fw, const float* __restrict__ fb,
                          const float* __restrict__ ob, float* __restrict__ out) {
  int w = (blockIdx.x * 256 + threadIdx.x) >> 6;    // 0..1023
  int lane = threadIdx.x & 63;
  const float* row = fw + (long)w * 1024;
  float s = 0.f;
  for (int k = lane; k < 1024; k += 64) s += row[k] * ob[k];
#pragma unroll
  for (int m = 32; m >= 1; m >>= 1) s += __shfl_xor(s, m, 64);
  if (lane == 0) out[w] = fb[w] + s;
}

// ---------------- split-K reduce into 1024-wide AO: col block coloff --------
template<int KS>
__global__ __launch_bounds__(256) void k_ksum(const float* __restrict__ P,
                                              u16* __restrict__ O, long n, int coloff) {
  long i = ((long)blockIdx.x * 256 + threadIdx.x) * 4;
  if (i >= n) return;
  float4 s = *(const float4*)(P + i);
#pragma unroll
  for (int ks = 1; ks < KS; ks++) {
    float4 t = *(const float4*)(P + (long)ks * n + i);
    s.x += t.x; s.y += t.y; s.z += t.z; s.w += t.w;
  }
  ushort4 o;
  o.x = f2bf(s.x); o.y = f2bf(s.y); o.z = f2bf(s.z); o.w = f2bf(s.w);
  *(ushort4*)(O + (i >> 8) * 1024 + coloff + (int)(i & 255)) = o;
}

// ---------------- block reduction helper (256 threads = 4 waves) ------------
__device__ __forceinline__ float block_allreduce(float x, bool domax) {
  __shared__ float t[4];
  int lane = threadIdx.x & 63, w = threadIdx.x >> 6;
#pragma unroll
  for (int m = 32; m >= 1; m >>= 1) {
    float o = __shfl_xor(x, m, 64);
    x = domax ? fmaxf(x, o) : (x + o);
  }
  __syncthreads();
  if (lane == 0) t[w] = x;
  __syncthreads();
  return domax ? fmaxf(fmaxf(t[0], t[1]), fmaxf(t[2], t[3]))
               : (t[0] + t[1] + t[2] + t[3]);
}

// ---------------- in-place row softmax over bf16 scores ----------------
template<int LK>
__global__ __launch_bounds__(256) void k_softmax(u16* __restrict__ P) {
  constexpr int E = LK / 256;
  long row = blockIdx.x;
  u16* p = P + row * (long)LK;
  int tid = threadIdx.x;
  float v[E];
  float mx = -1e30f;
#pragma unroll
  for (int i = 0; i < E; i++) { v[i] = bf2f(p[tid + i * 256]); mx = fmaxf(mx, v[i]); }
  mx = block_allreduce(mx, true);
  float s = 0.f;
#pragma unroll
  for (int i = 0; i < E; i++) { v[i] = __expf(v[i] - mx); s += v[i]; }
  s = block_allreduce(s, false);
  float inv = 1.0f / s;
#pragma unroll
  for (int i = 0; i < E; i++) p[tid + i * 256] = f2bf(v[i] * inv);
}

// scale-0 softmax: both heads of one (b,q) row; also writes fp32 head-mean W0
__global__ __launch_bounds__(256) void k_softmax0(u16* __restrict__ P, float* __restrict__ W0) {
  int bq = blockIdx.x;          // 0..8191
  int b = bq >> 11, q = bq & 2047;
  int tid = threadIdx.x;
  float pw[2][8];
  for (int h = 0; h < 2; h++) {
    u16* p = P + (((long)(b * 2 + h) * 2048 + q) * 2048);
    float v[8];
    float mx = -1e30f;
#pragma unroll
    for (int i = 0; i < 8; i++) { v[i] = bf2f(p[tid + i * 256]); mx = fmaxf(mx, v[i]); }
    mx = block_allreduce(mx, true);
    float s = 0.f;
#pragma unroll
    for (int i = 0; i < 8; i++) { v[i] = __expf(v[i] - mx); s += v[i]; }
    s = block_allreduce(s, false);
    float inv = 1.0f / s;
#pragma unroll
    for (int i = 0; i < 8; i++) { pw[h][i] = v[i] * inv; p[tid + i * 256] = f2bf(pw[h][i]); }
  }
  float* wrow = W0 + (long)bq * 2048;
#pragma unroll
  for (int i = 0; i < 8; i++) wrow[tid + i * 256] = 0.5f * (pw[0][i] + pw[1][i]);
}

// ---------------- 128x128-tile batched bf16 MFMA GEMM, global_load_lds staging ----
// C = alpha*(A . B^T) + bias.  z = ((z1*nz2)+z2)*KS + ks (split-K).
template<int WBF>
__global__ __launch_bounds__(256) void k_gemm(
    const u16* __restrict__ A, long ldA, long sA1, long sA2,
    const u16* __restrict__ B, long ldB, long sB1, long sB2,
    void* __restrict__ Cv, long ldC, long sC1, long sC2, long sCk,
    const float* __restrict__ bias, long sBias, float alpha,
    int M, int N, int K, int nz2, int KS)
{
  __shared__ u16 As[128][32];
  __shared__ u16 Bs[128][32];
  int z = blockIdx.z;
  int ks = z % KS; int zz = z / KS;
  int z1 = zz / nz2, z2 = zz - z1 * nz2;
  A += (long)z1 * sA1 + (long)z2 * sA2 + (long)ks * K;
  B += (long)z1 * sB1 + (long)z2 * sB2 + (long)ks * K;
  long coff = (long)z1 * sC1 + (long)z2 * sC2 + (long)ks * sCk;
  const float* bz = bias ? bias + (long)z2 * sBias : nullptr;
  const int m0 = blockIdx.y * 128, n0 = blockIdx.x * 128;
  const int tid = threadIdx.x;
  const int lane = tid & 63;
  const int wave = tid >> 6;
  const int wr = (wave >> 1) * 64, wc = (wave & 1) * 64;
  const int q4 = lane >> 4, l16 = lane & 15;

  const int srow = wave * 16 + (lane >> 2);
  const int scol = (lane & 3) * 8;
  const u16* gA = A + (long)(m0 + srow) * ldA + scol;
  const u16* gB = B + (long)(n0 + srow) * ldB + scol;
  lds_t* lA0 = (lds_t*)&As[wave * 16][0];
  lds_t* lA1 = (lds_t*)&As[64 + wave * 16][0];
  lds_t* lB0 = (lds_t*)&Bs[wave * 16][0];
  lds_t* lB1 = (lds_t*)&Bs[64 + wave * 16][0];

  v4f acc[4][4];
#pragma unroll
  for (int i = 0; i < 4; i++)
#pragma unroll
    for (int j = 0; j < 4; j++) acc[i][j] = (v4f){0.f, 0.f, 0.f, 0.f};

  for (int kt = 0; kt < K; kt += 32) {
    __builtin_amdgcn_global_load_lds((g_t*)(gA + kt), (lds_t*)lA0, 16, 0, 0);
    __builtin_amdgcn_global_load_lds((g_t*)(gA + 64 * ldA + kt), (lds_t*)lA1, 16, 0, 0);
    __builtin_amdgcn_global_load_lds((g_t*)(gB + kt), (lds_t*)lB0, 16, 0, 0);
    __builtin_amdgcn_global_load_lds((g_t*)(gB + 64 * ldB + kt), (lds_t*)lB1, 16, 0, 0);
    __syncthreads();
    v8bf af[4], bf[4];
#pragma unroll
    for (int i = 0; i < 4; i++) af[i] = *(const v8bf*)&As[wr + i * 16 + l16][q4 * 8];
#pragma unroll
    for (int i = 0; i < 4; i++) bf[i] = *(const v8bf*)&Bs[wc + i * 16 + l16][q4 * 8];
#pragma unroll
    for (int mi = 0; mi < 4; mi++)
#pragma unroll
      for (int ni = 0; ni < 4; ni++)
        acc[mi][ni] = __builtin_amdgcn_mfma_f32_16x16x32_bf16(af[mi], bf[ni], acc[mi][ni], 0, 0, 0);
    __syncthreads();
  }

#pragma unroll
  for (int mi = 0; mi < 4; mi++) {
    int rb = m0 + wr + mi * 16 + q4 * 4;
#pragma unroll
    for (int ni = 0; ni < 4; ni++) {
      int c = n0 + wc + ni * 16 + l16;
      float bv = bz ? bz[c] : 0.f;
#pragma unroll
      for (int i = 0; i < 4; i++) {
        int r = rb + i;
        float val = acc[mi][ni][i] * alpha + bv;
        if (WBF) ((u16*)Cv)[coff + (long)r * ldC + c] = f2bf(val);
        else     ((float*)Cv)[coff + (long)r * ldC + c] = val;
      }
    }
  }
}

// ---------------- 128x64-tile batched GEMM, per-z offsets/M (grouped) ----------
// TR=1: write transposed into (b,h,hd,Ls) with per-z Ls (power of 2).
template<int TR>
__global__ __launch_bounds__(256) void k_gemm_sm(
    const u16* __restrict__ A, long ldA, long4 aOff,
    const u16* __restrict__ B, long ldB, long sB,
    u16* __restrict__ C, long ldC, long4 cOff,
    const float* __restrict__ bias, long sBias,
    int4 Mz, int K, int4 Lsz)
{
  int z = blockIdx.z;
  int M = sel4i(Mz, z);
  int m0 = blockIdx.y * 128;
  if (m0 >= M) return;
  int n0 = blockIdx.x * 64;
  const u16* Az = A + sel4(aOff, z);
  const u16* Bz = B + (long)z * sB;
  long coff = sel4(cOff, z);
  const float* bz = bias + (long)z * sBias;
  int Ls = sel4i(Lsz, z);
  int lsh = 31 - __clz(Ls);

  __shared__ u16 As[128][32];
  __shared__ u16 Bs[64][32];
  const int tid = threadIdx.x;
  const int lane = tid & 63, wave = tid >> 6;
  const int q4 = lane >> 4, l16 = lane & 15;
  const int srow = wave * 16 + (lane >> 2);
  const int scol = (lane & 3) * 8;
  const u16* gA = Az + (long)(m0 + srow) * ldA + scol;
  const u16* gB = Bz + (long)(n0 + srow) * ldB + scol;
  lds_t* lA0 = (lds_t*)&As[wave * 16][0];
  lds_t* lA1 = (lds_t*)&As[64 + wave * 16][0];
  lds_t* lB0 = (lds_t*)&Bs[wave * 16][0];

  v4f acc[2][4];
#pragma unroll
  for (int i = 0; i < 2; i++)
#pragma unroll
    for (int j = 0; j < 4; j++) acc[i][j] = (v4f){0.f, 0.f, 0.f, 0.f};

  for (int kt = 0; kt < K; kt += 32) {
    __builtin_amdgcn_global_load_lds((g_t*)(gA + kt), (lds_t*)lA0, 16, 0, 0);
    __builtin_amdgcn_global_load_lds((g_t*)(gA + 64 * ldA + kt), (lds_t*)lA1, 16, 0, 0);
    __builtin_amdgcn_global_load_lds((g_t*)(gB + kt), (lds_t*)lB0, 16, 0, 0);
    __syncthreads();
    v8bf af[2], bf[4];
#pragma unroll
    for (int i = 0; i < 2; i++) af[i] = *(const v8bf*)&As[wave * 32 + i * 16 + l16][q4 * 8];
#pragma unroll
    for (int j = 0; j < 4; j++) bf[j] = *(const v8bf*)&Bs[j * 16 + l16][q4 * 8];
#pragma unroll
    for (int mi = 0; mi < 2; mi++)
#pragma unroll
      for (int ni = 0; ni < 4; ni++)
        acc[mi][ni] = __builtin_amdgcn_mfma_f32_16x16x32_bf16(af[mi], bf[ni], acc[mi][ni], 0, 0, 0);
    __syncthreads();
  }

#pragma unroll
  for (int mi = 0; mi < 2; mi++) {
    int rb = m0 + wave * 32 + mi * 16 + q4 * 4;
#pragma unroll
    for (int ni = 0; ni < 4; ni++) {
      int c = n0 + ni * 16 + l16;
      float bv = bz[c];
#pragma unroll
      for (int i = 0; i < 4; i++) {
        int r = rb + i;
        float val = acc[mi][ni][i] + bv;
        if (TR) {
          int b = r >> lsh, t = r & (Ls - 1);
          int h = c >> 7, n = c & 127;
          C[coff + (((long)(b * 2 + h) * 128 + n) << lsh) + t] = f2bf(val);
        } else {
          C[coff + (long)r * ldC + c] = f2bf(val);
        }
      }
    }
  }
}

extern "C" void kernel_launch(void* const* d_in, const int* in_sizes, int n_in,
                              void* d_out, int out_size, void* d_ws, size_t ws_size,
                              hipStream_t stream) {
  const float* query = (const float*)d_in[0];
  const float* key_  = (const float*)d_in[1];
  const float* value = (const float*)d_in[2];
  const float* wq    = (const float*)d_in[3];
  const float* bq    = (const float*)d_in[4];
  const float* wk    = (const float*)d_in[5];
  const float* bk    = (const float*)d_in[6];
  const float* wv    = (const float*)d_in[7];
  const float* bv    = (const float*)d_in[8];
  const float* in_w  = (const float*)d_in[9];
  const float* in_b  = (const float*)d_in[10];
  const float* out_w = (const float*)d_in[11];
  const float* out_b = (const float*)d_in[12];
  const float* fus_w = (const float*)d_in[13];
  const float* fus_b = (const float*)d_in[14];
  (void)in_sizes; (void)n_in; (void)out_size; (void)ws_size;

  float* outF  = (float*)d_out;
  float* outW0 = outF + (long)4 * 2048 * 1024;

  // ---- workspace layout (~173 MB) ----
  char* base = (char*)d_ws;
  size_t off = 0;
  auto alloc = [&](size_t bytes) -> void* {
    void* p = base + off;
    off = (off + bytes + 255) & ~(size_t)255;
    return p;
  };
  const long NX = (long)8192 * 1024;
  u16* Winb = (u16*)alloc((size_t)4 * 768 * 256 * 2);     // bf16 in_w
  u16* Wfb  = (u16*)alloc((size_t)1024 * 1024 * 2);       // bf16 fus_w
  u16* WoT  = (u16*)alloc((size_t)4 * 256 * 256 * 2);     // bf16 out_w^T (per scale)
  u16* WT   = (u16*)alloc((size_t)3 * 1024 * 1024 * 2);   // bf16 wq^T|wk^T|wv^T
  u16* WC   = (u16*)alloc((size_t)3 * 1024 * 1024 * 2);   // combined WQc|WKc|WVc
  u16* WFc  = (u16*)alloc((size_t)1024 * 1024 * 2);       // combined final weight
  float* Bc  = (float*)alloc((size_t)3 * 1024 * 4);       // combined bQc|bKc|bVc
  float* fbc = (float*)alloc((size_t)1024 * 4);           // combined final bias
  // region X: Xq(8192) + XkAll(15360) + XvAll(15360) rows x1024 bf16 = 76 MB
  // SC (67 MB) aliases it once head GEMMs are done.
  char* regX = (char*)alloc((size_t)(8192 + 2 * 15360) * 1024 * 2);
  u16* Xq    = (u16*)regX;
  u16* XkAll = Xq + NX;
  u16* XvAll = XkAll + (long)15360 * 1024;
  u16* SC    = (u16*)regX;
  u16* QHf = (u16*)alloc((size_t)8192 * 1024 * 2);        // heads of Q, 1024-wide
  u16* KH  = (u16*)alloc((size_t)15360 * 256 * 2);
  u16* VHT = (u16*)alloc((size_t)15360 * 256 * 2);
  float* PP = (float*)alloc((size_t)4 * 8192 * 256 * 4);  // split-K partials
  u16* AOf = (u16*)alloc((size_t)8192 * 1024 * 2);        // attended concat, 1024-wide

  const long rOff[4] = {0, 8192, 12288, 14336};           // row offsets per scale
  const long AOsz = (long)8192 * 256;

  // ---- converts / transposes / pooling ----
  k_cvt<<<1024, 256, 0, stream>>>(query, Xq, NX);
  k_cvt<<<1024, 256, 0, stream>>>(key_,  XkAll, NX);
  k_cvt<<<1024, 256, 0, stream>>>(value, XvAll, NX);
  k_cvt<<<192, 256, 0, stream>>>(in_w, Winb, 4 * 768 * 256);
  k_cvt<<<256, 256, 0, stream>>>(fus_w, Wfb, 1024 * 1024);
  k_tc<<<dim3(32, 32, 1), 256, 0, stream>>>(wq, WT, 1024, 1024);
  k_tc<<<dim3(32, 32, 1), 256, 0, stream>>>(wk, WT + (long)1024 * 1024, 1024, 1024);
  k_tc<<<dim3(32, 32, 1), 256, 0, stream>>>(wv, WT + (long)2 * 1024 * 1024, 1024, 1024);
  k_tc<<<dim3(8, 8, 4), 256, 0, stream>>>(out_w, WoT, 256, 256);
  k_pool3<<<4096, 256, 0, stream>>>(key_,  XkAll);   // pooled rows 8192..15360
  k_pool3<<<4096, 256, 0, stream>>>(value, XvAll);
  k_bcomb_qkv<<<768, 256, 0, stream>>>(in_w, in_b, bq, bk, bv, Bc);
  k_bcomb_f<<<256, 256, 0, stream>>>(fus_w, fus_b, out_b, fbc);

  // ---- weight combines ----
  // WC[p][i] (256x1024) = in_w[i][p*256:(p+1)*256] @ w_p[256i:256(i+1), :]
  k_gemm<1><<<dim3(8, 2, 12), 256, 0, stream>>>(
      Winb, 256, 65536, 196608,
      WT, 1024, 1048576, 256,
      WC, 1024, 1048576, 262144, 0,
      nullptr, 0, 1.f, 256, 1024, 256, 4, 1);
  // WFc[:, 256i:256(i+1)] = fus_w[:, 256i:256(i+1)] @ out_w[i]
  k_gemm<1><<<dim3(2, 8, 4), 256, 0, stream>>>(
      Wfb, 1024, 0, 256,
      WoT, 256, 0, 65536,
      WFc, 1024, 0, 256, 0,
      nullptr, 0, 1.f, 1024, 256, 256, 4, 1);

  // ---- head projections (fused: eliminates q/k/v full proj + in-proj) ----
  // QHf = Xq @ WQc_all^T + bQc : one 8192x1024x1024 GEMM
  k_gemm<1><<<dim3(8, 64, 1), 256, 0, stream>>>(
      Xq, 1024, 0, 0, WC, 1024, 0, 0,
      QHf, 1024, 0, 0, 0, Bc, 0, 1.f, 8192, 1024, 1024, 1, 1);
  {
    long4 aK = {0, (long)8192 * 1024, (long)12288 * 1024, (long)14336 * 1024};
    long4 cK = {0, (long)8192 * 256, (long)12288 * 256, (long)14336 * 256};
    int4  mP = {8192, 4096, 2048, 1024};
    int4  ls1 = {1, 1, 1, 1};
    int4  lsv = {2048, 1024, 512, 256};
    // KH_i = pool_i(key) @ WKc_i^T + bKc_i   (grouped over scales, K=1024)
    k_gemm_sm<0><<<dim3(4, 64, 4), 256, 0, stream>>>(
        XkAll, 1024, aK, WC + (long)1024 * 1024, 1024, 262144,
        KH, 256, cK, Bc + 1024, 256, mP, 1024, ls1);
    // VHT_i = (pool_i(value) @ WVc_i^T + bVc_i) transposed to (b,h,hd,Ls)
    k_gemm_sm<1><<<dim3(4, 64, 4), 256, 0, stream>>>(
        XvAll, 1024, aK, WC + (long)2 * 1024 * 1024, 1024, 262144,
        VHT, 0, cK, Bc + 2048, 256, mP, 1024, lsv);
  }

  // ---- per-scale attention ----
  const int ksArr[4] = {4, 4, 2, 2};
  for (int i = 0; i < 4; i++) {
    int Lk = 2048 >> i;
    // scores = qh . kh^T / sqrt(128): grid (Lk/128, 16, 8)
    k_gemm<1><<<dim3(Lk / 128, 16, 8), 256, 0, stream>>>(
        QHf + (long)i * 256, 1024, (long)2048 * 1024, 128,
        KH + rOff[i] * 256, 256, (long)Lk * 256, 128,
        SC, Lk, (long)2 * 2048 * Lk, (long)2048 * Lk, 0,
        nullptr, 0, 0.08838834764831845f, 2048, Lk, 128, 2, 1);
    if (i == 0)      k_softmax0<<<8192, 256, 0, stream>>>(SC, outW0);
    else if (i == 1) k_softmax<1024><<<16384, 256, 0, stream>>>(SC);
    else if (i == 2) k_softmax<512><<<16384, 256, 0, stream>>>(SC);
    else             k_softmax<256><<<16384, 256, 0, stream>>>(SC);
    // PV with split-K: fp32 partials, grid (1, 16, 8*KS)
    int KS = ksArr[i], Kper = Lk / KS;
    k_gemm<0><<<dim3(1, 16, 8 * KS), 256, 0, stream>>>(
        SC, Lk, (long)2 * 2048 * Lk, (long)2048 * Lk,
        VHT + rOff[i] * 256, Lk, (long)2 * 128 * Lk, (long)128 * Lk,
        PP, 256, (long)2048 * 256, 128, AOsz,
        nullptr, 0, 1.f, 2048, 128, Kper, 2, KS);
    if (KS == 4) k_ksum<4><<<2048, 256, 0, stream>>>(PP, AOf, AOsz, i * 256);
    else         k_ksum<2><<<2048, 256, 0, stream>>>(PP, AOf, AOsz, i * 256);
  }

  // ---- final (fused out-proj + fusion): fused = AOf @ WFc^T + fbc ----
  k_gemm<0><<<dim3(8, 64, 1), 256, 0, stream>>>(
      AOf, 1024, 0, 0, WFc, 1024, 0, 0,
      outF, 1024, 0, 0, 0, fbc, 0, 1.f, 8192, 1024, 1024, 1, 1);
}

// Round 3
// 632.317 us; speedup vs baseline: 1.0918x; 1.0572x over previous
//
#include <hip/hip_runtime.h>
#include <stdint.h>

typedef unsigned short u16;
typedef __bf16 v8bf __attribute__((ext_vector_type(8)));
typedef float v4f __attribute__((ext_vector_type(4)));
typedef __attribute__((address_space(3))) unsigned lds_t;
typedef const __attribute__((address_space(1))) unsigned g_t;

__device__ __forceinline__ u16 f2bf(float f) {
  union { float f; unsigned u; } v; v.f = f;
  unsigned r = v.u + 0x7FFFu + ((v.u >> 16) & 1u);   // RNE
  return (u16)(r >> 16);
}
__device__ __forceinline__ float bf2f(u16 h) {
  union { unsigned u; float f; } v; v.u = ((unsigned)h) << 16;
  return v.f;
}
__device__ __forceinline__ ushort4 f4bf(float4 f) {
  ushort4 o;
  o.x = f2bf(f.x); o.y = f2bf(f.y); o.z = f2bf(f.z); o.w = f2bf(f.w);
  return o;
}
__device__ __forceinline__ long sel4(long4 v, int z) {
  return z == 0 ? v.x : z == 1 ? v.y : z == 2 ? v.z : v.w;
}
__device__ __forceinline__ int sel4i(int4 v, int z) {
  return z == 0 ? v.x : z == 1 ? v.y : z == 2 ? v.z : v.w;
}

// ---------------- fp32 -> bf16 convert ----------------
__global__ void k_cvt(const float* __restrict__ s, u16* __restrict__ d, long n) {
  long i = ((long)blockIdx.x * blockDim.x + threadIdx.x) * 4;
  long stride = (long)gridDim.x * blockDim.x * 4;
  for (; i < n; i += stride) {
    *(ushort4*)(d + i) = f4bf(*(const float4*)(s + i));
  }
}

// ---------------- fused convert + 3-level pool (key/value) ----------------
// src: (4,2048,1024) fp32, read ONCE. dst bf16 rows:
//   full-res: b*2048+t ; s=2: 8192+b*1024+t' ; s=4: 12288+b*512+t' ; s=8: 14336+b*256+t'
// grid 1024 (= b*256 + g), 256 thr; thread handles 4 cols x 8 rows.
__global__ void k_cvtpool(const float* __restrict__ src, u16* __restrict__ dst) {
  int g = blockIdx.x & 255, b = blockIdx.x >> 8;
  int c = threadIdx.x * 4;
  const float* p = src + ((long)b * 2048 + g * 8) * 1024 + c;
  u16* df = dst + ((long)b * 2048 + g * 8) * 1024 + c;
  float4 x[8];
#pragma unroll
  for (int j = 0; j < 8; j++) {
    x[j] = *(const float4*)(p + (long)j * 1024);
    *(ushort4*)(df + (long)j * 1024) = f4bf(x[j]);
  }
  float4 s2[4], s4[2], s8;
#pragma unroll
  for (int j = 0; j < 4; j++) {
    s2[j].x = x[2 * j].x + x[2 * j + 1].x;
    s2[j].y = x[2 * j].y + x[2 * j + 1].y;
    s2[j].z = x[2 * j].z + x[2 * j + 1].z;
    s2[j].w = x[2 * j].w + x[2 * j + 1].w;
  }
#pragma unroll
  for (int j = 0; j < 2; j++) {
    s4[j].x = s2[2 * j].x + s2[2 * j + 1].x;
    s4[j].y = s2[2 * j].y + s2[2 * j + 1].y;
    s4[j].z = s2[2 * j].z + s2[2 * j + 1].z;
    s4[j].w = s2[2 * j].w + s2[2 * j + 1].w;
  }
  s8.x = s4[0].x + s4[1].x; s8.y = s4[0].y + s4[1].y;
  s8.z = s4[0].z + s4[1].z; s8.w = s4[0].w + s4[1].w;
  u16* d2 = dst + ((long)8192 + b * 1024 + g * 4) * 1024 + c;
#pragma unroll
  for (int j = 0; j < 4; j++) {
    float4 t = {s2[j].x * 0.5f, s2[j].y * 0.5f, s2[j].z * 0.5f, s2[j].w * 0.5f};
    *(ushort4*)(d2 + (long)j * 1024) = f4bf(t);
  }
  u16* d4 = dst + ((long)12288 + b * 512 + g * 2) * 1024 + c;
#pragma unroll
  for (int j = 0; j < 2; j++) {
    float4 t = {s4[j].x * 0.25f, s4[j].y * 0.25f, s4[j].z * 0.25f, s4[j].w * 0.25f};
    *(ushort4*)(d4 + (long)j * 1024) = f4bf(t);
  }
  float4 t8 = {s8.x * 0.125f, s8.y * 0.125f, s8.z * 0.125f, s8.w * 0.125f};
  *(ushort4*)(dst + ((long)14336 + b * 256 + g) * 1024 + c) = f4bf(t8);
}

// ---------------- fp32 -> bf16 transpose-convert (32x32 tiles, batched z) ----
__global__ void k_tc(const float* __restrict__ src, u16* __restrict__ dst, int R, int C) {
  __shared__ float t[32][33];
  long zoff = (long)blockIdx.z * R * C;
  int r0 = blockIdx.y * 32, c0 = blockIdx.x * 32;
  int tx = threadIdx.x & 31, ty = threadIdx.x >> 5;     // ty in [0,8)
#pragma unroll
  for (int j = 0; j < 32; j += 8)
    t[ty + j][tx] = src[zoff + (long)(r0 + ty + j) * C + c0 + tx];
  __syncthreads();
#pragma unroll
  for (int j = 0; j < 32; j += 8)
    dst[zoff + (long)(c0 + ty + j) * R + r0 + tx] = f2bf(t[tx][ty + j]);
}

// ---------------- bias combines (fp32) ----------------
__global__ void k_bcomb_qkv(const float* __restrict__ in_w, const float* __restrict__ in_b,
                            const float* __restrict__ bq, const float* __restrict__ bk,
                            const float* __restrict__ bv, float* __restrict__ out) {
  int gw = (blockIdx.x * 256 + threadIdx.x) >> 6;   // 0..3071
  int lane = threadIdx.x & 63;
  int p = gw >> 10, j = gw & 1023, i = j >> 8, of = j & 255;
  const float* bp = p == 0 ? bq : p == 1 ? bk : bv;
  const float* row = in_w + ((long)i * 768 + p * 256 + of) * 256;
  float s = 0.f;
#pragma unroll
  for (int m = 0; m < 4; m++) s += row[lane + m * 64] * bp[i * 256 + lane + m * 64];
#pragma unroll
  for (int m = 32; m >= 1; m >>= 1) s += __shfl_xor(s, m, 64);
  if (lane == 0) out[gw] = in_b[(long)i * 768 + p * 256 + of] + s;
}

__global__ void k_bcomb_f(const float* __restrict__ fw, const float* __restrict__ fb,
                          const float* __restrict__ ob, float* __restrict__ out) {
  int w = (blockIdx.x * 256 + threadIdx.x) >> 6;    // 0..1023
  int lane = threadIdx.x & 63;
  const float* row = fw + (long)w * 1024;
  float s = 0.f;
  for (int k = lane; k < 1024; k += 64) s += row[k] * ob[k];
#pragma unroll
  for (int m = 32; m >= 1; m >>= 1) s += __shfl_xor(s, m, 64);
  if (lane == 0) out[w] = fb[w] + s;
}

// ---------------- split-K reduce into 1024-wide AO: col block coloff --------
template<int KS>
__global__ __launch_bounds__(256) void k_ksum(const float* __restrict__ P,
                                              u16* __restrict__ O, long n, int coloff) {
  long i = ((long)blockIdx.x * 256 + threadIdx.x) * 4;
  if (i >= n) return;
  float4 s = *(const float4*)(P + i);
#pragma unroll
  for (int ks = 1; ks < KS; ks++) {
    float4 t = *(const float4*)(P + (long)ks * n + i);
    s.x += t.x; s.y += t.y; s.z += t.z; s.w += t.w;
  }
  *(ushort4*)(O + (i >> 8) * 1024 + coloff + (int)(i & 255)) = f4bf(s);
}

// ---------------- block reduction helper (256 threads = 4 waves) ------------
__device__ __forceinline__ float block_allreduce(float x, bool domax) {
  __shared__ float t[4];
  int lane = threadIdx.x & 63, w = threadIdx.x >> 6;
#pragma unroll
  for (int m = 32; m >= 1; m >>= 1) {
    float o = __shfl_xor(x, m, 64);
    x = domax ? fmaxf(x, o) : (x + o);
  }
  __syncthreads();
  if (lane == 0) t[w] = x;
  __syncthreads();
  return domax ? fmaxf(fmaxf(t[0], t[1]), fmaxf(t[2], t[3]))
               : (t[0] + t[1] + t[2] + t[3]);
}

// ---------------- in-place row softmax over bf16 scores ----------------
template<int LK>
__global__ __launch_bounds__(256) void k_softmax(u16* __restrict__ P) {
  constexpr int E = LK / 256;
  long row = blockIdx.x;
  u16* p = P + row * (long)LK;
  int tid = threadIdx.x;
  float v[E];
  float mx = -1e30f;
#pragma unroll
  for (int i = 0; i < E; i++) { v[i] = bf2f(p[tid + i * 256]); mx = fmaxf(mx, v[i]); }
  mx = block_allreduce(mx, true);
  float s = 0.f;
#pragma unroll
  for (int i = 0; i < E; i++) { v[i] = __expf(v[i] - mx); s += v[i]; }
  s = block_allreduce(s, false);
  float inv = 1.0f / s;
#pragma unroll
  for (int i = 0; i < E; i++) p[tid + i * 256] = f2bf(v[i] * inv);
}

// scale-0 softmax: both heads of one (b,q) row; also writes fp32 head-mean W0
__global__ __launch_bounds__(256) void k_softmax0(u16* __restrict__ P, float* __restrict__ W0) {
  int bq = blockIdx.x;          // 0..8191
  int b = bq >> 11, q = bq & 2047;
  int tid = threadIdx.x;
  float pw[2][8];
  for (int h = 0; h < 2; h++) {
    u16* p = P + (((long)(b * 2 + h) * 2048 + q) * 2048);
    float v[8];
    float mx = -1e30f;
#pragma unroll
    for (int i = 0; i < 8; i++) { v[i] = bf2f(p[tid + i * 256]); mx = fmaxf(mx, v[i]); }
    mx = block_allreduce(mx, true);
    float s = 0.f;
#pragma unroll
    for (int i = 0; i < 8; i++) { v[i] = __expf(v[i] - mx); s += v[i]; }
    s = block_allreduce(s, false);
    float inv = 1.0f / s;
#pragma unroll
    for (int i = 0; i < 8; i++) { pw[h][i] = v[i] * inv; p[tid + i * 256] = f2bf(pw[h][i]); }
  }
  float* wrow = W0 + (long)bq * 2048;
#pragma unroll
  for (int i = 0; i < 8; i++) wrow[tid + i * 256] = 0.5f * (pw[0][i] + pw[1][i]);
}

// ---------------- 128x128-tile batched bf16 MFMA GEMM ----------------
// Double-buffered 2-phase K-loop (T3-minimum): stage(next) issued BEFORE
// ds_read+MFMA of current tile; single __syncthreads per K-step drains both.
// C = alpha*(A . B^T) + bias.  z = ((z1*nz2)+z2)*KS + ks (split-K).
template<int WBF>
__global__ __launch_bounds__(256) void k_gemm(
    const u16* __restrict__ A, long ldA, long sA1, long sA2,
    const u16* __restrict__ B, long ldB, long sB1, long sB2,
    void* __restrict__ Cv, long ldC, long sC1, long sC2, long sCk,
    const float* __restrict__ bias, long sBias, float alpha,
    int M, int N, int K, int nz2, int KS)
{
  __shared__ u16 As[2][128][32];
  __shared__ u16 Bs[2][128][32];
  int z = blockIdx.z;
  int ks = z % KS; int zz = z / KS;
  int z1 = zz / nz2, z2 = zz - z1 * nz2;
  A += (long)z1 * sA1 + (long)z2 * sA2 + (long)ks * K;
  B += (long)z1 * sB1 + (long)z2 * sB2 + (long)ks * K;
  long coff = (long)z1 * sC1 + (long)z2 * sC2 + (long)ks * sCk;
  const float* bz = bias ? bias + (long)z2 * sBias : nullptr;
  const int m0 = blockIdx.y * 128, n0 = blockIdx.x * 128;
  const int tid = threadIdx.x;
  const int lane = tid & 63;
  const int wave = tid >> 6;
  const int wr = (wave >> 1) * 64, wc = (wave & 1) * 64;
  const int q4 = lane >> 4, l16 = lane & 15;

  const int srow = wave * 16 + (lane >> 2);
  const int scol = (lane & 3) * 8;
  const u16* gA = A + (long)(m0 + srow) * ldA + scol;
  const u16* gB = B + (long)(n0 + srow) * ldB + scol;

  auto stage = [&](int buf, int kt) {
    __builtin_amdgcn_global_load_lds((g_t*)(gA + kt), (lds_t*)&As[buf][wave * 16][0], 16, 0, 0);
    __builtin_amdgcn_global_load_lds((g_t*)(gA + 64 * ldA + kt), (lds_t*)&As[buf][64 + wave * 16][0], 16, 0, 0);
    __builtin_amdgcn_global_load_lds((g_t*)(gB + kt), (lds_t*)&Bs[buf][wave * 16][0], 16, 0, 0);
    __builtin_amdgcn_global_load_lds((g_t*)(gB + 64 * ldB + kt), (lds_t*)&Bs[buf][64 + wave * 16][0], 16, 0, 0);
  };

  v4f acc[4][4];
#pragma unroll
  for (int i = 0; i < 4; i++)
#pragma unroll
    for (int j = 0; j < 4; j++) acc[i][j] = (v4f){0.f, 0.f, 0.f, 0.f};

  stage(0, 0);
  __syncthreads();
  int cur = 0;
  for (int kt = 0; kt < K; kt += 32) {
    if (kt + 32 < K) stage(cur ^ 1, kt + 32);      // prefetch next tile
    v8bf af[4], bf[4];
#pragma unroll
    for (int i = 0; i < 4; i++) af[i] = *(const v8bf*)&As[cur][wr + i * 16 + l16][q4 * 8];
#pragma unroll
    for (int i = 0; i < 4; i++) bf[i] = *(const v8bf*)&Bs[cur][wc + i * 16 + l16][q4 * 8];
#pragma unroll
    for (int mi = 0; mi < 4; mi++)
#pragma unroll
      for (int ni = 0; ni < 4; ni++)
        acc[mi][ni] = __builtin_amdgcn_mfma_f32_16x16x32_bf16(af[mi], bf[ni], acc[mi][ni], 0, 0, 0);
    __syncthreads();                                // drains vmcnt+lgkm after compute
    cur ^= 1;
  }

#pragma unroll
  for (int mi = 0; mi < 4; mi++) {
    int rb = m0 + wr + mi * 16 + q4 * 4;
#pragma unroll
    for (int ni = 0; ni < 4; ni++) {
      int c = n0 + wc + ni * 16 + l16;
      float bv = bz ? bz[c] : 0.f;
#pragma unroll
      for (int i = 0; i < 4; i++) {
        int r = rb + i;
        float val = acc[mi][ni][i] * alpha + bv;
        if (WBF) ((u16*)Cv)[coff + (long)r * ldC + c] = f2bf(val);
        else     ((float*)Cv)[coff + (long)r * ldC + c] = val;
      }
    }
  }
}

// ---------------- 128x64-tile batched GEMM, per-z offsets/M (grouped) ----------
// Double-buffered like k_gemm. TR=1: write transposed into (b,h,hd,Ls).
template<int TR>
__global__ __launch_bounds__(256) void k_gemm_sm(
    const u16* __restrict__ A, long ldA, long4 aOff,
    const u16* __restrict__ B, long ldB, long sB,
    u16* __restrict__ C, long ldC, long4 cOff,
    const float* __restrict__ bias, long sBias,
    int4 Mz, int K, int4 Lsz)
{
  int z = blockIdx.z;
  int M = sel4i(Mz, z);
  int m0 = blockIdx.y * 128;
  if (m0 >= M) return;
  int n0 = blockIdx.x * 64;
  const u16* Az = A + sel4(aOff, z);
  const u16* Bz = B + (long)z * sB;
  long coff = sel4(cOff, z);
  const float* bz = bias + (long)z * sBias;
  int Ls = sel4i(Lsz, z);
  int lsh = 31 - __clz(Ls);

  __shared__ u16 As[2][128][32];
  __shared__ u16 Bs[2][64][32];
  const int tid = threadIdx.x;
  const int lane = tid & 63, wave = tid >> 6;
  const int q4 = lane >> 4, l16 = lane & 15;
  const int srow = wave * 16 + (lane >> 2);
  const int scol = (lane & 3) * 8;
  const u16* gA = Az + (long)(m0 + srow) * ldA + scol;
  const u16* gB = Bz + (long)(n0 + srow) * ldB + scol;

  auto stage = [&](int buf, int kt) {
    __builtin_amdgcn_global_load_lds((g_t*)(gA + kt), (lds_t*)&As[buf][wave * 16][0], 16, 0, 0);
    __builtin_amdgcn_global_load_lds((g_t*)(gA + 64 * ldA + kt), (lds_t*)&As[buf][64 + wave * 16][0], 16, 0, 0);
    __builtin_amdgcn_global_load_lds((g_t*)(gB + kt), (lds_t*)&Bs[buf][wave * 16][0], 16, 0, 0);
  };

  v4f acc[2][4];
#pragma unroll
  for (int i = 0; i < 2; i++)
#pragma unroll
    for (int j = 0; j < 4; j++) acc[i][j] = (v4f){0.f, 0.f, 0.f, 0.f};

  stage(0, 0);
  __syncthreads();
  int cur = 0;
  for (int kt = 0; kt < K; kt += 32) {
    if (kt + 32 < K) stage(cur ^ 1, kt + 32);
    v8bf af[2], bf[4];
#pragma unroll
    for (int i = 0; i < 2; i++) af[i] = *(const v8bf*)&As[cur][wave * 32 + i * 16 + l16][q4 * 8];
#pragma unroll
    for (int j = 0; j < 4; j++) bf[j] = *(const v8bf*)&Bs[cur][j * 16 + l16][q4 * 8];
#pragma unroll
    for (int mi = 0; mi < 2; mi++)
#pragma unroll
      for (int ni = 0; ni < 4; ni++)
        acc[mi][ni] = __builtin_amdgcn_mfma_f32_16x16x32_bf16(af[mi], bf[ni], acc[mi][ni], 0, 0, 0);
    __syncthreads();
    cur ^= 1;
  }

#pragma unroll
  for (int mi = 0; mi < 2; mi++) {
    int rb = m0 + wave * 32 + mi * 16 + q4 * 4;
#pragma unroll
    for (int ni = 0; ni < 4; ni++) {
      int c = n0 + ni * 16 + l16;
      float bv = bz[c];
#pragma unroll
      for (int i = 0; i < 4; i++) {
        int r = rb + i;
        float val = acc[mi][ni][i] + bv;
        if (TR) {
          int b = r >> lsh, t = r & (Ls - 1);
          int h = c >> 7, n = c & 127;
          C[coff + (((long)(b * 2 + h) * 128 + n) << lsh) + t] = f2bf(val);
        } else {
          C[coff + (long)r * ldC + c] = f2bf(val);
        }
      }
    }
  }
}

extern "C" void kernel_launch(void* const* d_in, const int* in_sizes, int n_in,
                              void* d_out, int out_size, void* d_ws, size_t ws_size,
                              hipStream_t stream) {
  const float* query = (const float*)d_in[0];
  const float* key_  = (const float*)d_in[1];
  const float* value = (const float*)d_in[2];
  const float* wq    = (const float*)d_in[3];
  const float* bq    = (const float*)d_in[4];
  const float* wk    = (const float*)d_in[5];
  const float* bk    = (const float*)d_in[6];
  const float* wv    = (const float*)d_in[7];
  const float* bv    = (const float*)d_in[8];
  const float* in_w  = (const float*)d_in[9];
  const float* in_b  = (const float*)d_in[10];
  const float* out_w = (const float*)d_in[11];
  const float* out_b = (const float*)d_in[12];
  const float* fus_w = (const float*)d_in[13];
  const float* fus_b = (const float*)d_in[14];
  (void)in_sizes; (void)n_in; (void)out_size; (void)ws_size;

  float* outF  = (float*)d_out;
  float* outW0 = outF + (long)4 * 2048 * 1024;

  // ---- workspace layout (~173 MB) ----
  char* base = (char*)d_ws;
  size_t off = 0;
  auto alloc = [&](size_t bytes) -> void* {
    void* p = base + off;
    off = (off + bytes + 255) & ~(size_t)255;
    return p;
  };
  const long NX = (long)8192 * 1024;
  u16* Winb = (u16*)alloc((size_t)4 * 768 * 256 * 2);     // bf16 in_w
  u16* Wfb  = (u16*)alloc((size_t)1024 * 1024 * 2);       // bf16 fus_w
  u16* WoT  = (u16*)alloc((size_t)4 * 256 * 256 * 2);     // bf16 out_w^T (per scale)
  u16* WT   = (u16*)alloc((size_t)3 * 1024 * 1024 * 2);   // bf16 wq^T|wk^T|wv^T
  u16* WC   = (u16*)alloc((size_t)3 * 1024 * 1024 * 2);   // combined WQc|WKc|WVc
  u16* WFc  = (u16*)alloc((size_t)1024 * 1024 * 2);       // combined final weight
  float* Bc  = (float*)alloc((size_t)3 * 1024 * 4);       // combined bQc|bKc|bVc
  float* fbc = (float*)alloc((size_t)1024 * 4);           // combined final bias
  // region X: Xq(8192) + XkAll(15360) + XvAll(15360) rows x1024 bf16 = 76 MB
  // SC (67 MB) aliases it once head GEMMs are done.
  char* regX = (char*)alloc((size_t)(8192 + 2 * 15360) * 1024 * 2);
  u16* Xq    = (u16*)regX;
  u16* XkAll = Xq + NX;
  u16* XvAll = XkAll + (long)15360 * 1024;
  u16* SC    = (u16*)regX;
  u16* QHf = (u16*)alloc((size_t)8192 * 1024 * 2);        // heads of Q, 1024-wide
  u16* KH  = (u16*)alloc((size_t)15360 * 256 * 2);
  u16* VHT = (u16*)alloc((size_t)15360 * 256 * 2);
  float* PP = (float*)alloc((size_t)4 * 8192 * 256 * 4);  // split-K partials
  u16* AOf = (u16*)alloc((size_t)8192 * 1024 * 2);        // attended concat, 1024-wide

  const long rOff[4] = {0, 8192, 12288, 14336};           // row offsets per scale
  const long AOsz = (long)8192 * 256;

  // ---- converts / transposes / pooling ----
  k_cvt<<<1024, 256, 0, stream>>>(query, Xq, NX);
  k_cvtpool<<<1024, 256, 0, stream>>>(key_,  XkAll);   // full-res + pooled in one pass
  k_cvtpool<<<1024, 256, 0, stream>>>(value, XvAll);
  k_cvt<<<192, 256, 0, stream>>>(in_w, Winb, 4 * 768 * 256);
  k_cvt<<<256, 256, 0, stream>>>(fus_w, Wfb, 1024 * 1024);
  k_tc<<<dim3(32, 32, 1), 256, 0, stream>>>(wq, WT, 1024, 1024);
  k_tc<<<dim3(32, 32, 1), 256, 0, stream>>>(wk, WT + (long)1024 * 1024, 1024, 1024);
  k_tc<<<dim3(32, 32, 1), 256, 0, stream>>>(wv, WT + (long)2 * 1024 * 1024, 1024, 1024);
  k_tc<<<dim3(8, 8, 4), 256, 0, stream>>>(out_w, WoT, 256, 256);
  k_bcomb_qkv<<<768, 256, 0, stream>>>(in_w, in_b, bq, bk, bv, Bc);
  k_bcomb_f<<<256, 256, 0, stream>>>(fus_w, fus_b, out_b, fbc);

  // ---- weight combines ----
  // WC[p][i] (256x1024) = in_w[i][p*256:(p+1)*256] @ w_p[256i:256(i+1), :]
  k_gemm<1><<<dim3(8, 2, 12), 256, 0, stream>>>(
      Winb, 256, 65536, 196608,
      WT, 1024, 1048576, 256,
      WC, 1024, 1048576, 262144, 0,
      nullptr, 0, 1.f, 256, 1024, 256, 4, 1);
  // WFc[:, 256i:256(i+1)] = fus_w[:, 256i:256(i+1)] @ out_w[i]
  k_gemm<1><<<dim3(2, 8, 4), 256, 0, stream>>>(
      Wfb, 1024, 0, 256,
      WoT, 256, 0, 65536,
      WFc, 1024, 0, 256, 0,
      nullptr, 0, 1.f, 1024, 256, 256, 4, 1);

  // ---- head projections (fused: eliminates q/k/v full proj + in-proj) ----
  // QHf = Xq @ WQc_all^T + bQc : one 8192x1024x1024 GEMM
  k_gemm<1><<<dim3(8, 64, 1), 256, 0, stream>>>(
      Xq, 1024, 0, 0, WC, 1024, 0, 0,
      QHf, 1024, 0, 0, 0, Bc, 0, 1.f, 8192, 1024, 1024, 1, 1);
  {
    long4 aK = {0, (long)8192 * 1024, (long)12288 * 1024, (long)14336 * 1024};
    long4 cK = {0, (long)8192 * 256, (long)12288 * 256, (long)14336 * 256};
    int4  mP = {8192, 4096, 2048, 1024};
    int4  ls1 = {1, 1, 1, 1};
    int4  lsv = {2048, 1024, 512, 256};
    // KH_i = pool_i(key) @ WKc_i^T + bKc_i   (grouped over scales, K=1024)
    k_gemm_sm<0><<<dim3(4, 64, 4), 256, 0, stream>>>(
        XkAll, 1024, aK, WC + (long)1024 * 1024, 1024, 262144,
        KH, 256, cK, Bc + 1024, 256, mP, 1024, ls1);
    // VHT_i = (pool_i(value) @ WVc_i^T + bVc_i) transposed to (b,h,hd,Ls)
    k_gemm_sm<1><<<dim3(4, 64, 4), 256, 0, stream>>>(
        XvAll, 1024, aK, WC + (long)2 * 1024 * 1024, 1024, 262144,
        VHT, 0, cK, Bc + 2048, 256, mP, 1024, lsv);
  }

  // ---- per-scale attention ----
  const int ksArr[4] = {4, 4, 2, 2};
  for (int i = 0; i < 4; i++) {
    int Lk = 2048 >> i;
    // scores = qh . kh^T / sqrt(128): grid (Lk/128, 16, 8)
    k_gemm<1><<<dim3(Lk / 128, 16, 8), 256, 0, stream>>>(
        QHf + (long)i * 256, 1024, (long)2048 * 1024, 128,
        KH + rOff[i] * 256, 256, (long)Lk * 256, 128,
        SC, Lk, (long)2 * 2048 * Lk, (long)2048 * Lk, 0,
        nullptr, 0, 0.08838834764831845f, 2048, Lk, 128, 2, 1);
    if (i == 0)      k_softmax0<<<8192, 256, 0, stream>>>(SC, outW0);
    else if (i == 1) k_softmax<1024><<<16384, 256, 0, stream>>>(SC);
    else if (i == 2) k_softmax<512><<<16384, 256, 0, stream>>>(SC);
    else             k_softmax<256><<<16384, 256, 0, stream>>>(SC);
    // PV with split-K: fp32 partials, grid (1, 16, 8*KS)
    int KS = ksArr[i], Kper = Lk / KS;
    k_gemm<0><<<dim3(1, 16, 8 * KS), 256, 0, stream>>>(
        SC, Lk, (long)2 * 2048 * Lk, (long)2048 * Lk,
        VHT + rOff[i] * 256, Lk, (long)2 * 128 * Lk, (long)128 * Lk,
        PP, 256, (long)2048 * 256, 128, AOsz,
        nullptr, 0, 1.f, 2048, 128, Kper, 2, KS);
    if (KS == 4) k_ksum<4><<<2048, 256, 0, stream>>>(PP, AOf, AOsz, i * 256);
    else         k_ksum<2><<<2048, 256, 0, stream>>>(PP, AOf, AOsz, i * 256);
  }

  // ---- final (fused out-proj + fusion): fused = AOf @ WFc^T + fbc ----
  k_gemm<0><<<dim3(8, 64, 1), 256, 0, stream>>>(
      AOf, 1024, 0, 0, WFc, 1024, 0, 0,
      outF, 1024, 0, 0, 0, fbc, 0, 1.f, 8192, 1024, 1024, 1, 1);
}

// Round 4
// 532.230 us; speedup vs baseline: 1.2971x; 1.1881x over previous
//
#include <hip/hip_runtime.h>
#include <stdint.h>

typedef unsigned short u16;
typedef __bf16 v8bf __attribute__((ext_vector_type(8)));
typedef float v4f __attribute__((ext_vector_type(4)));
typedef __attribute__((address_space(3))) unsigned lds_t;
typedef const __attribute__((address_space(1))) unsigned g_t;

__device__ __forceinline__ u16 f2bf(float f) {
  union { float f; unsigned u; } v; v.f = f;
  unsigned r = v.u + 0x7FFFu + ((v.u >> 16) & 1u);   // RNE
  return (u16)(r >> 16);
}
__device__ __forceinline__ float bf2f(u16 h) {
  union { unsigned u; float f; } v; v.u = ((unsigned)h) << 16;
  return v.f;
}
__device__ __forceinline__ ushort4 f4bf(float4 f) {
  ushort4 o;
  o.x = f2bf(f.x); o.y = f2bf(f.y); o.z = f2bf(f.z); o.w = f2bf(f.w);
  return o;
}
__device__ __forceinline__ long sel4(long4 v, int z) {
  return z == 0 ? v.x : z == 1 ? v.y : z == 2 ? v.z : v.w;
}
__device__ __forceinline__ int sel4i(int4 v, int z) {
  return z == 0 ? v.x : z == 1 ? v.y : z == 2 ? v.z : v.w;
}

// ---------------- fp32 -> bf16 convert ----------------
__global__ void k_cvt(const float* __restrict__ s, u16* __restrict__ d, long n) {
  long i = ((long)blockIdx.x * blockDim.x + threadIdx.x) * 4;
  long stride = (long)gridDim.x * blockDim.x * 4;
  for (; i < n; i += stride) {
    *(ushort4*)(d + i) = f4bf(*(const float4*)(s + i));
  }
}

// ---------------- fused convert + 3-level pool (key/value) ----------------
__global__ void k_cvtpool(const float* __restrict__ src, u16* __restrict__ dst) {
  int g = blockIdx.x & 255, b = blockIdx.x >> 8;
  int c = threadIdx.x * 4;
  const float* p = src + ((long)b * 2048 + g * 8) * 1024 + c;
  u16* df = dst + ((long)b * 2048 + g * 8) * 1024 + c;
  float4 x[8];
#pragma unroll
  for (int j = 0; j < 8; j++) {
    x[j] = *(const float4*)(p + (long)j * 1024);
    *(ushort4*)(df + (long)j * 1024) = f4bf(x[j]);
  }
  float4 s2[4], s4[2], s8;
#pragma unroll
  for (int j = 0; j < 4; j++) {
    s2[j].x = x[2 * j].x + x[2 * j + 1].x;
    s2[j].y = x[2 * j].y + x[2 * j + 1].y;
    s2[j].z = x[2 * j].z + x[2 * j + 1].z;
    s2[j].w = x[2 * j].w + x[2 * j + 1].w;
  }
#pragma unroll
  for (int j = 0; j < 2; j++) {
    s4[j].x = s2[2 * j].x + s2[2 * j + 1].x;
    s4[j].y = s2[2 * j].y + s2[2 * j + 1].y;
    s4[j].z = s2[2 * j].z + s2[2 * j + 1].z;
    s4[j].w = s2[2 * j].w + s2[2 * j + 1].w;
  }
  s8.x = s4[0].x + s4[1].x; s8.y = s4[0].y + s4[1].y;
  s8.z = s4[0].z + s4[1].z; s8.w = s4[0].w + s4[1].w;
  u16* d2 = dst + ((long)8192 + b * 1024 + g * 4) * 1024 + c;
#pragma unroll
  for (int j = 0; j < 4; j++) {
    float4 t = {s2[j].x * 0.5f, s2[j].y * 0.5f, s2[j].z * 0.5f, s2[j].w * 0.5f};
    *(ushort4*)(d2 + (long)j * 1024) = f4bf(t);
  }
  u16* d4 = dst + ((long)12288 + b * 512 + g * 2) * 1024 + c;
#pragma unroll
  for (int j = 0; j < 2; j++) {
    float4 t = {s4[j].x * 0.25f, s4[j].y * 0.25f, s4[j].z * 0.25f, s4[j].w * 0.25f};
    *(ushort4*)(d4 + (long)j * 1024) = f4bf(t);
  }
  float4 t8 = {s8.x * 0.125f, s8.y * 0.125f, s8.z * 0.125f, s8.w * 0.125f};
  *(ushort4*)(dst + ((long)14336 + b * 256 + g) * 1024 + c) = f4bf(t8);
}

// ---------------- fp32 -> bf16 transpose-convert (32x32 tiles, batched z) ----
__global__ void k_tc(const float* __restrict__ src, u16* __restrict__ dst, int R, int C) {
  __shared__ float t[32][33];
  long zoff = (long)blockIdx.z * R * C;
  int r0 = blockIdx.y * 32, c0 = blockIdx.x * 32;
  int tx = threadIdx.x & 31, ty = threadIdx.x >> 5;
#pragma unroll
  for (int j = 0; j < 32; j += 8)
    t[ty + j][tx] = src[zoff + (long)(r0 + ty + j) * C + c0 + tx];
  __syncthreads();
#pragma unroll
  for (int j = 0; j < 32; j += 8)
    dst[zoff + (long)(c0 + ty + j) * R + r0 + tx] = f2bf(t[tx][ty + j]);
}

// ---------------- bias combines (fp32) ----------------
__global__ void k_bcomb_qkv(const float* __restrict__ in_w, const float* __restrict__ in_b,
                            const float* __restrict__ bq, const float* __restrict__ bk,
                            const float* __restrict__ bv, float* __restrict__ out) {
  int gw = (blockIdx.x * 256 + threadIdx.x) >> 6;   // 0..3071
  int lane = threadIdx.x & 63;
  int p = gw >> 10, j = gw & 1023, i = j >> 8, of = j & 255;
  const float* bp = p == 0 ? bq : p == 1 ? bk : bv;
  const float* row = in_w + ((long)i * 768 + p * 256 + of) * 256;
  float s = 0.f;
#pragma unroll
  for (int m = 0; m < 4; m++) s += row[lane + m * 64] * bp[i * 256 + lane + m * 64];
#pragma unroll
  for (int m = 32; m >= 1; m >>= 1) s += __shfl_xor(s, m, 64);
  if (lane == 0) out[gw] = in_b[(long)i * 768 + p * 256 + of] + s;
}

__global__ void k_bcomb_f(const float* __restrict__ fw, const float* __restrict__ fb,
                          const float* __restrict__ ob, float* __restrict__ out) {
  int w = (blockIdx.x * 256 + threadIdx.x) >> 6;    // 0..1023
  int lane = threadIdx.x & 63;
  const float* row = fw + (long)w * 1024;
  float s = 0.f;
  for (int k = lane; k < 1024; k += 64) s += row[k] * ob[k];
#pragma unroll
  for (int m = 32; m >= 1; m >>= 1) s += __shfl_xor(s, m, 64);
  if (lane == 0) out[w] = fb[w] + s;
}

// ---------------- split-K reduce into 1024-wide AO (scale 0 only) ----------
template<int KS>
__global__ __launch_bounds__(256) void k_ksum(const float* __restrict__ P,
                                              u16* __restrict__ O, long n, int coloff) {
  long i = ((long)blockIdx.x * 256 + threadIdx.x) * 4;
  if (i >= n) return;
  float4 s = *(const float4*)(P + i);
#pragma unroll
  for (int ks = 1; ks < KS; ks++) {
    float4 t = *(const float4*)(P + (long)ks * n + i);
    s.x += t.x; s.y += t.y; s.z += t.z; s.w += t.w;
  }
  *(ushort4*)(O + (i >> 8) * 1024 + coloff + (int)(i & 255)) = f4bf(s);
}

// ---------------- block reduction helper (256 threads = 4 waves) ------------
__device__ __forceinline__ float block_allreduce(float x, bool domax) {
  __shared__ float t[4];
  int lane = threadIdx.x & 63, w = threadIdx.x >> 6;
#pragma unroll
  for (int m = 32; m >= 1; m >>= 1) {
    float o = __shfl_xor(x, m, 64);
    x = domax ? fmaxf(x, o) : (x + o);
  }
  __syncthreads();
  if (lane == 0) t[w] = x;
  __syncthreads();
  return domax ? fmaxf(fmaxf(t[0], t[1]), fmaxf(t[2], t[3]))
               : (t[0] + t[1] + t[2] + t[3]);
}

// scale-0 softmax: both heads of one (b,q) row; also writes fp32 head-mean W0
__global__ __launch_bounds__(256) void k_softmax0(u16* __restrict__ P, float* __restrict__ W0) {
  int bq = blockIdx.x;          // 0..8191
  int b = bq >> 11, q = bq & 2047;
  int tid = threadIdx.x;
  float pw[2][8];
  for (int h = 0; h < 2; h++) {
    u16* p = P + (((long)(b * 2 + h) * 2048 + q) * 2048);
    float v[8];
    float mx = -1e30f;
#pragma unroll
    for (int i = 0; i < 8; i++) { v[i] = bf2f(p[tid + i * 256]); mx = fmaxf(mx, v[i]); }
    mx = block_allreduce(mx, true);
    float s = 0.f;
#pragma unroll
    for (int i = 0; i < 8; i++) { v[i] = __expf(v[i] - mx); s += v[i]; }
    s = block_allreduce(s, false);
    float inv = 1.0f / s;
#pragma unroll
    for (int i = 0; i < 8; i++) { pw[h][i] = v[i] * inv; p[tid + i * 256] = f2bf(pw[h][i]); }
  }
  float* wrow = W0 + (long)bq * 2048;
#pragma unroll
  for (int i = 0; i < 8; i++) wrow[tid + i * 256] = 0.5f * (pw[0][i] + pw[1][i]);
}

// ---------------- flash attention for scales 1..3 ----------------
// grid (1, 32, 24): y = 64-row q-tile, z = (i-1)*8 + b*2 + h.  256 threads.
// Q-tile 64x128 (regs via LDS), K-tiles of 128, online softmax, O = P.V.
// Writes AOf[row][i*256 + h*128 + d].
__global__ __launch_bounds__(256) void k_flash(
    const u16* __restrict__ QHf, const u16* __restrict__ KH,
    const u16* __restrict__ VHT, u16* __restrict__ AOf)
{
  int z = blockIdx.z;
  int i = (z >> 3) + 1;                 // scale 1..3
  int b = (z >> 1) & 3, h = z & 1;
  int Ls = 2048 >> i;
  int nkt = Ls >> 7;                    // 8,4,2
  long ro = (long)(16384 - (8192 >> (i - 1))) * 256;   // 8192/12288/14336 rows
  int q0 = blockIdx.y * 64;

  __shared__ u16 QP[64][136];           // Q, then P (aliased); padded rows
  __shared__ u16 KV[2][128][32];        // K/V sub-tile staging (shared K then V)
  __shared__ float red[2][4][64];       // [m|l][wave][row]

  const int tid = threadIdx.x, lane = tid & 63, wave = tid >> 6;
  const int q4 = lane >> 4, l16 = lane & 15;
  const int wr = (wave >> 1) * 32, wc = (wave & 1) * 64;
  const int srow = wave * 16 + (lane >> 2);
  const int scol = (lane & 3) * 8;

  // ---- stage Q once (reg-staged; padded LDS), hoist fragments to regs ----
  {
    const u16* gq = QHf + ((long)b * 2048 + q0) * 1024 + i * 256 + h * 128;
    int idx = tid * 4;
#pragma unroll
    for (int j = 0; j < 4; j++) {
      int r = (idx + j) >> 4, ch = (idx + j) & 15;
      *(ulonglong2*)&QP[r][ch * 8] = *(const ulonglong2*)(gq + (long)r * 1024 + ch * 8);
    }
  }
  __syncthreads();
  v8bf qf[2][4];
#pragma unroll
  for (int mi = 0; mi < 2; mi++)
#pragma unroll
    for (int sub = 0; sub < 4; sub++)
      qf[mi][sub] = *(const v8bf*)&QP[wr + mi * 16 + l16][sub * 32 + q4 * 8];
  __syncthreads();                       // QP now reusable for P

  const u16* gK = KH + ro + (long)b * Ls * 256 + h * 128;
  const u16* gV = VHT + ro + (long)(b * 2 + h) * 128 * Ls;

  auto stageK = [&](int buf, int kt, int sub) {
    const u16* g = gK + (long)(kt * 128 + srow) * 256 + sub * 32 + scol;
    __builtin_amdgcn_global_load_lds((g_t*)g, (lds_t*)&KV[buf][wave * 16][0], 16, 0, 0);
    __builtin_amdgcn_global_load_lds((g_t*)(g + 64 * 256), (lds_t*)&KV[buf][64 + wave * 16][0], 16, 0, 0);
  };
  auto stageV = [&](int buf, int kt, int sub) {
    const u16* g = gV + (long)srow * Ls + kt * 128 + sub * 32 + scol;
    __builtin_amdgcn_global_load_lds((g_t*)g, (lds_t*)&KV[buf][wave * 16][0], 16, 0, 0);
    __builtin_amdgcn_global_load_lds((g_t*)(g + (long)64 * Ls), (lds_t*)&KV[buf][64 + wave * 16][0], 16, 0, 0);
  };

  v4f acc_o[2][4];
  float m_run[2][4], l_run[2][4];
#pragma unroll
  for (int mi = 0; mi < 2; mi++)
#pragma unroll
    for (int ni = 0; ni < 4; ni++) acc_o[mi][ni] = (v4f){0.f, 0.f, 0.f, 0.f};
#pragma unroll
  for (int mi = 0; mi < 2; mi++)
#pragma unroll
    for (int i4 = 0; i4 < 4; i4++) { m_run[mi][i4] = -1e30f; l_run[mi][i4] = 0.f; }

  const float alpha = 0.08838834764831845f;

  for (int kt = 0; kt < nkt; kt++) {
    // ---- S = Q . K^T ----
    v4f s[2][4];
#pragma unroll
    for (int mi = 0; mi < 2; mi++)
#pragma unroll
      for (int ni = 0; ni < 4; ni++) s[mi][ni] = (v4f){0.f, 0.f, 0.f, 0.f};
    stageK(0, kt, 0);
    __syncthreads();
    int cur = 0;
#pragma unroll
    for (int sub = 0; sub < 4; sub++) {
      if (sub < 3) stageK(cur ^ 1, kt, sub + 1);
      v8bf kf[4];
#pragma unroll
      for (int ni = 0; ni < 4; ni++)
        kf[ni] = *(const v8bf*)&KV[cur][wc + ni * 16 + l16][q4 * 8];
#pragma unroll
      for (int mi = 0; mi < 2; mi++)
#pragma unroll
        for (int ni = 0; ni < 4; ni++)
          s[mi][ni] = __builtin_amdgcn_mfma_f32_16x16x32_bf16(qf[mi][sub], kf[ni], s[mi][ni], 0, 0, 0);
      __syncthreads();
      cur ^= 1;
    }
    stageV(0, kt, 0);                    // prefetch V sub0 under softmax

    // ---- online softmax over rows ----
#pragma unroll
    for (int mi = 0; mi < 2; mi++)
#pragma unroll
      for (int ni = 0; ni < 4; ni++) s[mi][ni] *= alpha;
    float mloc[2][4];
#pragma unroll
    for (int mi = 0; mi < 2; mi++)
#pragma unroll
      for (int i4 = 0; i4 < 4; i4++)
        mloc[mi][i4] = fmaxf(fmaxf(s[mi][0][i4], s[mi][1][i4]),
                             fmaxf(s[mi][2][i4], s[mi][3][i4]));
#pragma unroll
    for (int d = 1; d <= 8; d <<= 1)
#pragma unroll
      for (int mi = 0; mi < 2; mi++)
#pragma unroll
        for (int i4 = 0; i4 < 4; i4++)
          mloc[mi][i4] = fmaxf(mloc[mi][i4], __shfl_xor(mloc[mi][i4], d, 64));
    if (l16 == 0) {
#pragma unroll
      for (int mi = 0; mi < 2; mi++)
#pragma unroll
        for (int i4 = 0; i4 < 4; i4++)
          red[0][wave][wr + mi * 16 + q4 * 4 + i4] = mloc[mi][i4];
    }
    __syncthreads();
    float scl[2][4];
#pragma unroll
    for (int mi = 0; mi < 2; mi++)
#pragma unroll
      for (int i4 = 0; i4 < 4; i4++) {
        int rr = wr + mi * 16 + q4 * 4 + i4;
        float mn = fmaxf(fmaxf(red[0][wave][rr], red[0][wave ^ 1][rr]), m_run[mi][i4]);
        scl[mi][i4] = __expf(m_run[mi][i4] - mn);
        m_run[mi][i4] = mn;
      }
    float lloc[2][4] = {{0.f, 0.f, 0.f, 0.f}, {0.f, 0.f, 0.f, 0.f}};
#pragma unroll
    for (int mi = 0; mi < 2; mi++)
#pragma unroll
      for (int ni = 0; ni < 4; ni++)
#pragma unroll
        for (int i4 = 0; i4 < 4; i4++) {
          float p = __expf(s[mi][ni][i4] - m_run[mi][i4]);
          lloc[mi][i4] += p;
          QP[wr + mi * 16 + q4 * 4 + i4][wc + ni * 16 + l16] = f2bf(p);
        }
#pragma unroll
    for (int d = 1; d <= 8; d <<= 1)
#pragma unroll
      for (int mi = 0; mi < 2; mi++)
#pragma unroll
        for (int i4 = 0; i4 < 4; i4++)
          lloc[mi][i4] += __shfl_xor(lloc[mi][i4], d, 64);
    if (l16 == 0) {
#pragma unroll
      for (int mi = 0; mi < 2; mi++)
#pragma unroll
        for (int i4 = 0; i4 < 4; i4++)
          red[1][wave][wr + mi * 16 + q4 * 4 + i4] = lloc[mi][i4];
    }
    // rescale O while l-partials settle
#pragma unroll
    for (int mi = 0; mi < 2; mi++)
#pragma unroll
      for (int ni = 0; ni < 4; ni++)
#pragma unroll
        for (int i4 = 0; i4 < 4; i4++) acc_o[mi][ni][i4] *= scl[mi][i4];
    __syncthreads();                    // P + l-partials visible; V sub0 arrived
#pragma unroll
    for (int mi = 0; mi < 2; mi++)
#pragma unroll
      for (int i4 = 0; i4 < 4; i4++) {
        int rr = wr + mi * 16 + q4 * 4 + i4;
        l_run[mi][i4] = l_run[mi][i4] * scl[mi][i4] + red[1][wave][rr] + red[1][wave ^ 1][rr];
      }

    // ---- O += P . V ----
    int cv = 0;
#pragma unroll
    for (int sub = 0; sub < 4; sub++) {
      if (sub < 3) stageV(cv ^ 1, kt, sub + 1);
      v8bf pf[2], vf[4];
#pragma unroll
      for (int mi = 0; mi < 2; mi++)
        pf[mi] = *(const v8bf*)&QP[wr + mi * 16 + l16][sub * 32 + q4 * 8];
#pragma unroll
      for (int ni = 0; ni < 4; ni++)
        vf[ni] = *(const v8bf*)&KV[cv][wc + ni * 16 + l16][q4 * 8];
#pragma unroll
      for (int mi = 0; mi < 2; mi++)
#pragma unroll
        for (int ni = 0; ni < 4; ni++)
          acc_o[mi][ni] = __builtin_amdgcn_mfma_f32_16x16x32_bf16(pf[mi], vf[ni], acc_o[mi][ni], 0, 0, 0);
      __syncthreads();
      cv ^= 1;
    }
  }

  // ---- normalize + write ----
#pragma unroll
  for (int mi = 0; mi < 2; mi++)
#pragma unroll
    for (int i4 = 0; i4 < 4; i4++) {
      float inv = 1.0f / l_run[mi][i4];
#pragma unroll
      for (int ni = 0; ni < 4; ni++) {
        int r = q0 + wr + mi * 16 + q4 * 4 + i4;
        int c = wc + ni * 16 + l16;
        AOf[((long)b * 2048 + r) * 1024 + i * 256 + h * 128 + c] =
            f2bf(acc_o[mi][ni][i4] * inv);
      }
    }
}

// ---------------- 128x128-tile batched bf16 MFMA GEMM (double-buffered) ----
template<int WBF>
__global__ __launch_bounds__(256) void k_gemm(
    const u16* __restrict__ A, long ldA, long sA1, long sA2,
    const u16* __restrict__ B, long ldB, long sB1, long sB2,
    void* __restrict__ Cv, long ldC, long sC1, long sC2, long sCk,
    const float* __restrict__ bias, long sBias, float alpha,
    int M, int N, int K, int nz2, int KS)
{
  __shared__ u16 As[2][128][32];
  __shared__ u16 Bs[2][128][32];
  int z = blockIdx.z;
  int ks = z % KS; int zz = z / KS;
  int z1 = zz / nz2, z2 = zz - z1 * nz2;
  A += (long)z1 * sA1 + (long)z2 * sA2 + (long)ks * K;
  B += (long)z1 * sB1 + (long)z2 * sB2 + (long)ks * K;
  long coff = (long)z1 * sC1 + (long)z2 * sC2 + (long)ks * sCk;
  const float* bz = bias ? bias + (long)z2 * sBias : nullptr;
  const int m0 = blockIdx.y * 128, n0 = blockIdx.x * 128;
  const int tid = threadIdx.x;
  const int lane = tid & 63;
  const int wave = tid >> 6;
  const int wr = (wave >> 1) * 64, wc = (wave & 1) * 64;
  const int q4 = lane >> 4, l16 = lane & 15;

  const int srow = wave * 16 + (lane >> 2);
  const int scol = (lane & 3) * 8;
  const u16* gA = A + (long)(m0 + srow) * ldA + scol;
  const u16* gB = B + (long)(n0 + srow) * ldB + scol;

  auto stage = [&](int buf, int kt) {
    __builtin_amdgcn_global_load_lds((g_t*)(gA + kt), (lds_t*)&As[buf][wave * 16][0], 16, 0, 0);
    __builtin_amdgcn_global_load_lds((g_t*)(gA + 64 * ldA + kt), (lds_t*)&As[buf][64 + wave * 16][0], 16, 0, 0);
    __builtin_amdgcn_global_load_lds((g_t*)(gB + kt), (lds_t*)&Bs[buf][wave * 16][0], 16, 0, 0);
    __builtin_amdgcn_global_load_lds((g_t*)(gB + 64 * ldB + kt), (lds_t*)&Bs[buf][64 + wave * 16][0], 16, 0, 0);
  };

  v4f acc[4][4];
#pragma unroll
  for (int i = 0; i < 4; i++)
#pragma unroll
    for (int j = 0; j < 4; j++) acc[i][j] = (v4f){0.f, 0.f, 0.f, 0.f};

  stage(0, 0);
  __syncthreads();
  int cur = 0;
  for (int kt = 0; kt < K; kt += 32) {
    if (kt + 32 < K) stage(cur ^ 1, kt + 32);
    v8bf af[4], bf[4];
#pragma unroll
    for (int i = 0; i < 4; i++) af[i] = *(const v8bf*)&As[cur][wr + i * 16 + l16][q4 * 8];
#pragma unroll
    for (int i = 0; i < 4; i++) bf[i] = *(const v8bf*)&Bs[cur][wc + i * 16 + l16][q4 * 8];
#pragma unroll
    for (int mi = 0; mi < 4; mi++)
#pragma unroll
      for (int ni = 0; ni < 4; ni++)
        acc[mi][ni] = __builtin_amdgcn_mfma_f32_16x16x32_bf16(af[mi], bf[ni], acc[mi][ni], 0, 0, 0);
    __syncthreads();
    cur ^= 1;
  }

#pragma unroll
  for (int mi = 0; mi < 4; mi++) {
    int rb = m0 + wr + mi * 16 + q4 * 4;
#pragma unroll
    for (int ni = 0; ni < 4; ni++) {
      int c = n0 + wc + ni * 16 + l16;
      float bv = bz ? bz[c] : 0.f;
#pragma unroll
      for (int i = 0; i < 4; i++) {
        int r = rb + i;
        float val = acc[mi][ni][i] * alpha + bv;
        if (WBF) ((u16*)Cv)[coff + (long)r * ldC + c] = f2bf(val);
        else     ((float*)Cv)[coff + (long)r * ldC + c] = val;
      }
    }
  }
}

// ---------------- 128x64-tile batched GEMM, per-z offsets/M (grouped) ----------
template<int TR>
__global__ __launch_bounds__(256) void k_gemm_sm(
    const u16* __restrict__ A, long ldA, long4 aOff,
    const u16* __restrict__ B, long ldB, long sB,
    u16* __restrict__ C, long ldC, long4 cOff,
    const float* __restrict__ bias, long sBias,
    int4 Mz, int K, int4 Lsz)
{
  int z = blockIdx.z;
  int M = sel4i(Mz, z);
  int m0 = blockIdx.y * 128;
  if (m0 >= M) return;
  int n0 = blockIdx.x * 64;
  const u16* Az = A + sel4(aOff, z);
  const u16* Bz = B + (long)z * sB;
  long coff = sel4(cOff, z);
  const float* bz = bias + (long)z * sBias;
  int Ls = sel4i(Lsz, z);
  int lsh = 31 - __clz(Ls);

  __shared__ u16 As[2][128][32];
  __shared__ u16 Bs[2][64][32];
  const int tid = threadIdx.x;
  const int lane = tid & 63, wave = tid >> 6;
  const int q4 = lane >> 4, l16 = lane & 15;
  const int srow = wave * 16 + (lane >> 2);
  const int scol = (lane & 3) * 8;
  const u16* gA = Az + (long)(m0 + srow) * ldA + scol;
  const u16* gB = Bz + (long)(n0 + srow) * ldB + scol;

  auto stage = [&](int buf, int kt) {
    __builtin_amdgcn_global_load_lds((g_t*)(gA + kt), (lds_t*)&As[buf][wave * 16][0], 16, 0, 0);
    __builtin_amdgcn_global_load_lds((g_t*)(gA + 64 * ldA + kt), (lds_t*)&As[buf][64 + wave * 16][0], 16, 0, 0);
    __builtin_amdgcn_global_load_lds((g_t*)(gB + kt), (lds_t*)&Bs[buf][wave * 16][0], 16, 0, 0);
  };

  v4f acc[2][4];
#pragma unroll
  for (int i = 0; i < 2; i++)
#pragma unroll
    for (int j = 0; j < 4; j++) acc[i][j] = (v4f){0.f, 0.f, 0.f, 0.f};

  stage(0, 0);
  __syncthreads();
  int cur = 0;
  for (int kt = 0; kt < K; kt += 32) {
    if (kt + 32 < K) stage(cur ^ 1, kt + 32);
    v8bf af[2], bf[4];
#pragma unroll
    for (int i = 0; i < 2; i++) af[i] = *(const v8bf*)&As[cur][wave * 32 + i * 16 + l16][q4 * 8];
#pragma unroll
    for (int j = 0; j < 4; j++) bf[j] = *(const v8bf*)&Bs[cur][j * 16 + l16][q4 * 8];
#pragma unroll
    for (int mi = 0; mi < 2; mi++)
#pragma unroll
      for (int ni = 0; ni < 4; ni++)
        acc[mi][ni] = __builtin_amdgcn_mfma_f32_16x16x32_bf16(af[mi], bf[ni], acc[mi][ni], 0, 0, 0);
    __syncthreads();
    cur ^= 1;
  }

#pragma unroll
  for (int mi = 0; mi < 2; mi++) {
    int rb = m0 + wave * 32 + mi * 16 + q4 * 4;
#pragma unroll
    for (int ni = 0; ni < 4; ni++) {
      int c = n0 + ni * 16 + l16;
      float bv = bz[c];
#pragma unroll
      for (int i = 0; i < 4; i++) {
        int r = rb + i;
        float val = acc[mi][ni][i] + bv;
        if (TR) {
          int b = r >> lsh, t = r & (Ls - 1);
          int h = c >> 7, n = c & 127;
          C[coff + (((long)(b * 2 + h) * 128 + n) << lsh) + t] = f2bf(val);
        } else {
          C[coff + (long)r * ldC + c] = f2bf(val);
        }
      }
    }
  }
}

extern "C" void kernel_launch(void* const* d_in, const int* in_sizes, int n_in,
                              void* d_out, int out_size, void* d_ws, size_t ws_size,
                              hipStream_t stream) {
  const float* query = (const float*)d_in[0];
  const float* key_  = (const float*)d_in[1];
  const float* value = (const float*)d_in[2];
  const float* wq    = (const float*)d_in[3];
  const float* bq    = (const float*)d_in[4];
  const float* wk    = (const float*)d_in[5];
  const float* bk    = (const float*)d_in[6];
  const float* wv    = (const float*)d_in[7];
  const float* bv    = (const float*)d_in[8];
  const float* in_w  = (const float*)d_in[9];
  const float* in_b  = (const float*)d_in[10];
  const float* out_w = (const float*)d_in[11];
  const float* out_b = (const float*)d_in[12];
  const float* fus_w = (const float*)d_in[13];
  const float* fus_b = (const float*)d_in[14];
  (void)in_sizes; (void)n_in; (void)out_size; (void)ws_size;

  float* outF  = (float*)d_out;
  float* outW0 = outF + (long)4 * 2048 * 1024;

  // ---- workspace layout ----
  char* base = (char*)d_ws;
  size_t off = 0;
  auto alloc = [&](size_t bytes) -> void* {
    void* p = base + off;
    off = (off + bytes + 255) & ~(size_t)255;
    return p;
  };
  const long NX = (long)8192 * 1024;
  u16* Winb = (u16*)alloc((size_t)4 * 768 * 256 * 2);     // bf16 in_w
  u16* Wfb  = (u16*)alloc((size_t)1024 * 1024 * 2);       // bf16 fus_w
  u16* WoT  = (u16*)alloc((size_t)4 * 256 * 256 * 2);     // bf16 out_w^T (per scale)
  u16* WT   = (u16*)alloc((size_t)3 * 1024 * 1024 * 2);   // bf16 wq^T|wk^T|wv^T
  u16* WC   = (u16*)alloc((size_t)3 * 1024 * 1024 * 2);   // combined WQc|WKc|WVc
  u16* WFc  = (u16*)alloc((size_t)1024 * 1024 * 2);       // combined final weight
  float* Bc  = (float*)alloc((size_t)3 * 1024 * 4);       // combined bQc|bKc|bVc
  float* fbc = (float*)alloc((size_t)1024 * 4);           // combined final bias
  // region X: Xq(8192) + XkAll(15360) + XvAll(15360) rows x1024 bf16 = 76 MB
  // SC (scale-0 only, 67 MB) aliases it once head GEMMs are done.
  char* regX = (char*)alloc((size_t)(8192 + 2 * 15360) * 1024 * 2);
  u16* Xq    = (u16*)regX;
  u16* XkAll = Xq + NX;
  u16* XvAll = XkAll + (long)15360 * 1024;
  u16* SC    = (u16*)regX;
  u16* QHf = (u16*)alloc((size_t)8192 * 1024 * 2);        // heads of Q, 1024-wide
  u16* KH  = (u16*)alloc((size_t)15360 * 256 * 2);
  u16* VHT = (u16*)alloc((size_t)15360 * 256 * 2);
  float* PP = (float*)alloc((size_t)4 * 8192 * 256 * 4);  // split-K partials (scale 0)
  u16* AOf = (u16*)alloc((size_t)8192 * 1024 * 2);        // attended concat, 1024-wide

  const long AOsz = (long)8192 * 256;

  // ---- converts / transposes / pooling ----
  k_cvt<<<1024, 256, 0, stream>>>(query, Xq, NX);
  k_cvtpool<<<1024, 256, 0, stream>>>(key_,  XkAll);   // full-res + pooled in one pass
  k_cvtpool<<<1024, 256, 0, stream>>>(value, XvAll);
  k_cvt<<<192, 256, 0, stream>>>(in_w, Winb, 4 * 768 * 256);
  k_cvt<<<256, 256, 0, stream>>>(fus_w, Wfb, 1024 * 1024);
  k_tc<<<dim3(32, 32, 1), 256, 0, stream>>>(wq, WT, 1024, 1024);
  k_tc<<<dim3(32, 32, 1), 256, 0, stream>>>(wk, WT + (long)1024 * 1024, 1024, 1024);
  k_tc<<<dim3(32, 32, 1), 256, 0, stream>>>(wv, WT + (long)2 * 1024 * 1024, 1024, 1024);
  k_tc<<<dim3(8, 8, 4), 256, 0, stream>>>(out_w, WoT, 256, 256);
  k_bcomb_qkv<<<768, 256, 0, stream>>>(in_w, in_b, bq, bk, bv, Bc);
  k_bcomb_f<<<256, 256, 0, stream>>>(fus_w, fus_b, out_b, fbc);

  // ---- weight combines ----
  k_gemm<1><<<dim3(8, 2, 12), 256, 0, stream>>>(
      Winb, 256, 65536, 196608,
      WT, 1024, 1048576, 256,
      WC, 1024, 1048576, 262144, 0,
      nullptr, 0, 1.f, 256, 1024, 256, 4, 1);
  k_gemm<1><<<dim3(2, 8, 4), 256, 0, stream>>>(
      Wfb, 1024, 0, 256,
      WoT, 256, 0, 65536,
      WFc, 1024, 0, 256, 0,
      nullptr, 0, 1.f, 1024, 256, 256, 4, 1);

  // ---- head projections ----
  k_gemm<1><<<dim3(8, 64, 1), 256, 0, stream>>>(
      Xq, 1024, 0, 0, WC, 1024, 0, 0,
      QHf, 1024, 0, 0, 0, Bc, 0, 1.f, 8192, 1024, 1024, 1, 1);
  {
    long4 aK = {0, (long)8192 * 1024, (long)12288 * 1024, (long)14336 * 1024};
    long4 cK = {0, (long)8192 * 256, (long)12288 * 256, (long)14336 * 256};
    int4  mP = {8192, 4096, 2048, 1024};
    int4  ls1 = {1, 1, 1, 1};
    int4  lsv = {2048, 1024, 512, 256};
    k_gemm_sm<0><<<dim3(4, 64, 4), 256, 0, stream>>>(
        XkAll, 1024, aK, WC + (long)1024 * 1024, 1024, 262144,
        KH, 256, cK, Bc + 1024, 256, mP, 1024, ls1);
    k_gemm_sm<1><<<dim3(4, 64, 4), 256, 0, stream>>>(
        XvAll, 1024, aK, WC + (long)2 * 1024 * 1024, 1024, 262144,
        VHT, 0, cK, Bc + 2048, 256, mP, 1024, lsv);
  }

  // ---- scale 0: materialized (weights0 output needs full softmax matrix) ----
  {
    k_gemm<1><<<dim3(16, 16, 8), 256, 0, stream>>>(
        QHf, 1024, (long)2048 * 1024, 128,
        KH, 256, (long)2048 * 256, 128,
        SC, 2048, (long)2 * 2048 * 2048, (long)2048 * 2048, 0,
        nullptr, 0, 0.08838834764831845f, 2048, 2048, 128, 2, 1);
    k_softmax0<<<8192, 256, 0, stream>>>(SC, outW0);
    k_gemm<0><<<dim3(1, 16, 32), 256, 0, stream>>>(
        SC, 2048, (long)2 * 2048 * 2048, (long)2048 * 2048,
        VHT, 2048, (long)2 * 128 * 2048, (long)128 * 2048,
        PP, 256, (long)2048 * 256, 128, AOsz,
        nullptr, 0, 1.f, 2048, 128, 512, 2, 4);
    k_ksum<4><<<2048, 256, 0, stream>>>(PP, AOf, AOsz, 0);
  }

  // ---- scales 1..3: fused flash attention ----
  k_flash<<<dim3(1, 32, 24), 256, 0, stream>>>(QHf, KH, VHT, AOf);

  // ---- final (fused out-proj + fusion): fused = AOf @ WFc^T + fbc ----
  k_gemm<0><<<dim3(8, 64, 1), 256, 0, stream>>>(
      AOf, 1024, 0, 0, WFc, 1024, 0, 0,
      outF, 1024, 0, 0, 0, fbc, 0, 1.f, 8192, 1024, 1024, 1, 1);
}